// Round 9
// baseline (357.434 us; speedup 1.0000x reference)
//
#include <hip/hip_runtime.h>
#include <hip/hip_fp16.h>
#include <cstdint>
#include <cstddef>

// ---------------------------------------------------------------------------
// GCN regression. Round 27: slice-phased gather for XCD-L2 locality.
// Invariant from R22-R26: all gather structures plateau at FETCH~82MB @
// ~1.1-1.2 TB/s beyond-L2 with everything else idle => beyond-L2 random-line
// service is the limiter; the lever is FETCH_SIZE (per-XCD L2 hit rate).
// Change: group_kernel counting-sorts each node's edge list by src-slice
// (8 slices of ~N/8 nodes ~ 1.6MB of rows each) and emits sliceoff[N][8].
// Gather kernels start at slice (blockIdx.x & 7) [= XCD on MI355X] and wrap:
// slices are contiguous, so this is just TWO contiguous ranges
// [split,end) + [beg,split) through the proven chunk loop. Co-resident
// blocks on an XCD share a phase -> its L2 holds ~2 slices, not 12.8MB.
// Correctness is ordering-independent (same edge set, reordered).
// Everything else byte-identical to R26 (345us; sc0 kept, was neutral).
// ---------------------------------------------------------------------------

#define BKT_LG 8
#define BKT_SZ 256
#define BIN_CHUNK 2048

#define XLD 68    // X row stride in halves (64 + 4 pad)
#define HLD 132   // H1 row stride in halves (128 + 4 pad)

using half2v = decltype(__builtin_amdgcn_cvt_pkrtz(0.0f, 0.0f));
typedef _Float16 half4v __attribute__((ext_vector_type(4)));
typedef float floatx4 __attribute__((ext_vector_type(4)));

#define MFMA16(a, b, c) __builtin_amdgcn_mfma_f32_16x16x16f16((a), (b), (c), 0, 0, 0)

#if __has_builtin(__builtin_amdgcn_fdot2)
#define FDOT2(a, b, c) __builtin_amdgcn_fdot2((a), (b), (c), false)
#else
__device__ __forceinline__ float fdot2_emul(half2v a, half2v b, float c) {
    return c + (float)a[0] * (float)b[0] + (float)a[1] * (float)b[1];
}
#define FDOT2(a, b, c) fdot2_emul((a), (b), (c))
#endif

__device__ __forceinline__ half2v i2h(int i) { union { int i; half2v h; } u; u.i = i; return u.h; }
__device__ __forceinline__ int h2i(half2v h) { union { int i; half2v h; } u; u.h = h; return u.i; }
__device__ __forceinline__ int pk2i(float a, float b) { return h2i(__builtin_amdgcn_cvt_pkrtz(a, b)); }

__device__ __forceinline__ void f4toh4(__half* p, float4 v) {
    union { uint2 u; __half2 h[2]; } cv;
    cv.h[0] = __floats2half2_rn(v.x, v.y);
    cv.h[1] = __floats2half2_rn(v.z, v.w);
    *(uint2*)p = cv.u;
}

__device__ __forceinline__ half4v lda4(const __half* p) {
    union { uint2 u; half4v h; } w;
    w.u = *(const uint2*)p;
    return w.h;
}

// L1-bypass 8B load: issue only. NOT READY until a vmcnt wait.
__device__ __forceinline__ void ld8_sc0(uint64_t& r, const void* p) {
    asm volatile("global_load_dwordx2 %0, %1, off sc0" : "=&v"(r) : "v"(p));
}
__device__ __forceinline__ void vm_wait0() {
    asm volatile("s_waitcnt vmcnt(0)" ::: "memory");
    __builtin_amdgcn_sched_barrier(0);
}

// ---- bucket histogram: bcnt[b] = #edges with dst in bucket b
static __global__ void bhist_kernel(const int* __restrict__ dst, int* __restrict__ bcnt,
                                    int E, int NB) {
    __shared__ int h[512];
    for (int i = threadIdx.x; i < NB; i += 256) h[i] = 0;
    __syncthreads();
    for (int t = blockIdx.x * 256 + threadIdx.x; t < E; t += gridDim.x * 256)
        atomicAdd(&h[dst[t] >> BKT_LG], 1);
    __syncthreads();
    for (int i = threadIdx.x; i < NB; i += 256)
        if (h[i]) atomicAdd(&bcnt[i], h[i]);
}

// ---- exclusive scan of bcnt -> base (NB+1), bfill = base  (single block, 512)
static __global__ void bscan_kernel(const int* __restrict__ bcnt, int* __restrict__ base,
                                    int* __restrict__ bfill, int NB, int E) {
    __shared__ int s[512];
    int t = threadIdx.x;
    int v = (t < NB) ? bcnt[t] : 0;
    s[t] = v;
    __syncthreads();
    for (int off = 1; off < 512; off <<= 1) {
        int u = (t >= off) ? s[t - off] : 0;
        __syncthreads();
        s[t] += u;
        __syncthreads();
    }
    if (t < NB) { base[t] = s[t] - v; bfill[t] = s[t] - v; }
    if (t == 0) base[NB] = E;
}

// ---- bin edges into bucket-contiguous runs
__launch_bounds__(256)
static __global__ void bin_kernel(const int* __restrict__ src, const int* __restrict__ dst,
                                  int* __restrict__ bfill, unsigned* __restrict__ binned,
                                  int E, int NB) {
    __shared__ int h[512];
    __shared__ int res[512];
    const int beg = blockIdx.x * BIN_CHUNK;
    const int ce = min(BIN_CHUNK, E - beg);
    for (int i = threadIdx.x; i < NB; i += 256) h[i] = 0;
    __syncthreads();
    for (int i = threadIdx.x; i < ce; i += 256)
        atomicAdd(&h[dst[beg + i] >> BKT_LG], 1);
    __syncthreads();
    for (int i = threadIdx.x; i < NB; i += 256) {
        res[i] = h[i] ? atomicAdd(&bfill[i], h[i]) : 0;
        h[i] = 0;
    }
    __syncthreads();
    for (int i = threadIdx.x; i < ce; i += 256) {
        int d = dst[beg + i];
        int b = d >> BKT_LG;
        int p = res[b] + atomicAdd(&h[b], 1);
        binned[p] = ((unsigned)src[beg + i] << BKT_LG) | (unsigned)(d & (BKT_SZ - 1));
    }
}

// ---- per-bucket (256 nodes): count per (node,slice), scan, emit rowptr/dinv/
//      sliceoff, scatter col in (node, src-slice) order.
__launch_bounds__(256)
static __global__ void group_kernel(const unsigned* __restrict__ binned, const int* __restrict__ base,
                                    int* __restrict__ rowptr, int* __restrict__ col,
                                    float* __restrict__ dinv, int* __restrict__ sliceoff,
                                    int Ns, int N, int E) {
    __shared__ int cnt2[BKT_SZ][8];   // 8 KB
    __shared__ int ex2[BKT_SZ][8];    // 8 KB (absolute col positions)
    __shared__ int ps[256];
    const int tid = threadIdx.x;
    const int b = blockIdx.x;
    const int node0 = b << BKT_LG;
    const int nn = min(BKT_SZ, N - node0);
    const int beg = base[b], end = base[b + 1];

    for (int i = tid; i < BKT_SZ * 8; i += 256) ((int*)cnt2)[i] = 0;
    __syncthreads();
    for (int i = beg + tid; i < end; i += 256) {
        unsigned v = binned[i];
        int srcn = (int)(v >> BKT_LG);
        atomicAdd(&cnt2[v & (BKT_SZ - 1)][srcn / Ns], 1);
    }
    __syncthreads();

    int c = 0;
#pragma unroll
    for (int s = 0; s < 8; ++s) c += cnt2[tid][s];
    ps[tid] = c;
    __syncthreads();
    for (int off = 1; off < 256; off <<= 1) {
        int u = (tid >= off) ? ps[tid - off] : 0;
        __syncthreads();
        ps[tid] += u;
        __syncthreads();
    }
    int excl = ps[tid] - c;

    int pos = beg + excl;
#pragma unroll
    for (int s = 0; s < 8; ++s) {
        ex2[tid][s] = pos;
        if (tid < nn) sliceoff[(size_t)(node0 + tid) * 8 + s] = pos;
        pos += cnt2[tid][s];
    }
    if (tid < nn) {
        rowptr[node0 + tid] = beg + excl;
        dinv[node0 + tid] = rsqrtf((float)c + 1.0f);
    }
    if (b == 0 && tid == 0) rowptr[N] = E;
    __syncthreads();

    for (int i = beg + tid; i < end; i += 256) {
        unsigned v = binned[i];
        int srcn = (int)(v >> BKT_LG);
        int p = atomicAdd(&ex2[v & (BKT_SZ - 1)][srcn / Ns], 1);
        col[p] = srcn;
    }
}

// o[row] = (half) x[row] * dinv[row], dim 64
static __global__ void scale_kernel(const float* __restrict__ x, const float* __restrict__ dinv,
                                    __half* __restrict__ o, int N) {
    int t = blockIdx.x * 256 + threadIdx.x;
    if (t >= N * 16) return;
    int row = t >> 4;
    int c = (t & 15) * 4;
    float d = dinv[row];
    float4 v = *(const float4*)&x[(size_t)row * 64 + c];
    v.x *= d; v.y *= d; v.z *= d; v.w *= d;
    f4toh4(&o[(size_t)row * 64 + c], v);
}

// ---- prepack W1/W2: fp16 transposed. Wt1 [128][64] @0, Wt2 [64][128] @8192.
static __global__ void wprep12_kernel(const float* __restrict__ W1, const float* __restrict__ W2,
                                      __half* __restrict__ Wt) {
    int i = blockIdx.x * 256 + threadIdx.x;
    if (i < 8192) {
        int o = i >> 6, k = i & 63;
        Wt[i] = __float2half(W1[(size_t)k * 128 + o]);
    } else if (i < 16384) {
        int j = i - 8192, o = j >> 7, k = j & 127;
        Wt[i] = __float2half(W2[(size_t)k * 64 + o]);
    }
}

// ===========================================================================
// 16-lane/node gather, slice-phased: two contiguous ranges [split,end) then
// [beg,split), each via uniform 8-edge batched chunks with sc0 row loads.
// ===========================================================================
template <bool GBR>
__device__ __forceinline__ float4 gather64s(const __half* __restrict__ hs,
                                            const int* __restrict__ rowptr,
                                            const int* __restrict__ col,
                                            const float* __restrict__ dinv,
                                            const float* __restrict__ gbias,
                                            const int* __restrict__ sliceoff,
                                            int node, int lane, int phase, float& dv) {
    constexpr int K = 64;
    const int beg = rowptr[node];
    const int end = rowptr[node + 1];
    const int split = sliceoff[(size_t)node * 8 + phase];   // in [beg,end]
    const int lane8 = lane & 7;
    union U2 { uint2 u; __half2 h[2]; };
    union UQ { uint64_t q; __half2 h[2]; };
    U2 cv;
    cv.u = *(const uint2*)&hs[(size_t)node * K + lane * 4];   // self loop
    __half2 a0 = cv.h[0], a1 = cv.h[1];
    const __half2 z2 = __float2half2_rn(0.f);
    __half2 b0 = z2, b1 = z2;

    // two ranges: slices phase..7, then 0..phase-1 (contiguous in memory)
    int lo = split, hi = end;
#pragma unroll 1
    for (int pass = 0; pass < 2; ++pass) {
        int myc = (lo + lane8 < hi) ? col[lo + lane8] : 0;
        for (int e = lo; e < hi; e += 8) {
            const int rem = hi - e;                    // uniform per 16-lane group
            int nmyc = 0;
            if (e + 8 + lane8 < hi) nmyc = col[e + 8 + lane8];
            uint64_t v[8];
#pragma unroll
            for (int j = 0; j < 8; ++j) {
                int s = __shfl(myc, j, 16);            // clamped col: always safe
                ld8_sc0(v[j], &hs[(size_t)s * K + lane * 4]);
            }
            vm_wait0();
#pragma unroll
            for (int j = 0; j < 8; j += 2) {
                UQ x0, x1;
                x0.q = (j < rem) ? v[j] : 0ull;
                x1.q = (j + 1 < rem) ? v[j + 1] : 0ull;
                a0 = __hadd2(a0, x0.h[0]); a1 = __hadd2(a1, x0.h[1]);
                b0 = __hadd2(b0, x1.h[0]); b1 = __hadd2(b1, x1.h[1]);
            }
            myc = nmyc;
        }
        lo = beg; hi = split;
    }
    float2 fa0 = __half22float2(a0), fa1 = __half22float2(a1);
    float2 fb0 = __half22float2(b0), fb1 = __half22float2(b1);
    dv = dinv[node];
    float4 r;
    r.x = (fa0.x + fb0.x) * dv;
    r.y = (fa0.y + fb0.y) * dv;
    r.z = (fa1.x + fb1.x) * dv;
    r.w = (fa1.y + fb1.y) * dv;
    if (GBR) {
        float4 bv = *(const float4*)&gbias[lane * 4];
        r.x = fmaxf(r.x + bv.x, 0.f);
        r.y = fmaxf(r.y + bv.y, 0.f);
        r.z = fmaxf(r.z + bv.z, 0.f);
        r.w = fmaxf(r.w + bv.w, 0.f);
    }
    return r;
}

// ===========================================================================
// fgmm1: gather (slice-phased) -> LDS X -> MFMA GEMM1(+b1,relu) -> LDS H1
//        -> MFMA GEMM2 -> *dinv -> T2h.  512 threads = 32 nodes, 8 waves.
// ===========================================================================
__launch_bounds__(512)
static __global__ void fgmm1_kernel(const __half* __restrict__ hs, const int* __restrict__ rowptr,
                                    const int* __restrict__ col, const float* __restrict__ dinv,
                                    const int* __restrict__ sliceoff,
                                    const __half* __restrict__ Wt1, const __half* __restrict__ Wt2,
                                    const float* __restrict__ b1, __half* __restrict__ out, int N) {
    __shared__ __align__(16) __half X[32 * XLD];    // 4352 B
    __shared__ __align__(16) __half H1[32 * HLD];   // 8448 B
    const int tid = threadIdx.x;
    const int lane16 = tid & 15;
    const int nodei = tid >> 4;            // 0..31
    const int wbase = blockIdx.x * 32;
    const int phase = blockIdx.x & 7;      // XCD heuristic (perf-only)

    // ---- phase 1: gather, pack fp16, stage in LDS ----
    float dvg = 0.f;
    float4 r = make_float4(0.f, 0.f, 0.f, 0.f);
    if (wbase + nodei < N)
        r = gather64s<false>(hs, rowptr, col, dinv, nullptr, sliceoff,
                             wbase + nodei, lane16, phase, dvg);
    uint2 xp;
    xp.x = pk2i(r.x, r.y);
    xp.y = pk2i(r.z, r.w);
    *(uint2*)&X[nodei * XLD + 4 * lane16] = xp;
    __syncthreads();

    // ---- phase 2: GEMM1 (64->128) as MFMA tiles. wave w: nh=w&1, t in {w>>1, (w>>1)+4}
    const int w = tid >> 6;
    const int l = tid & 63;
    const int nd = l & 15;
    const int q = l >> 4;
    const int nh = w & 1;
    const int row = nh * 16 + nd;          // node index in block (B/D column)

    half4v bw[4];
#pragma unroll
    for (int s = 0; s < 4; ++s)
        bw[s] = lda4(&X[row * XLD + 16 * s + 4 * q]);

#pragma unroll
    for (int tt = 0; tt < 2; ++tt) {
        const int t = (w >> 1) + tt * 4;
        floatx4 acc = {0.f, 0.f, 0.f, 0.f};
#pragma unroll
        for (int s = 0; s < 4; ++s)
            acc = MFMA16(lda4(&Wt1[(size_t)(16 * t + nd) * 64 + 16 * s + 4 * q]), bw[s], acc);
        float4 bb = *(const float4*)&b1[16 * t + 4 * q];
        uint2 st;
        st.x = pk2i(fmaxf(acc[0] + bb.x, 0.f), fmaxf(acc[1] + bb.y, 0.f));
        st.y = pk2i(fmaxf(acc[2] + bb.z, 0.f), fmaxf(acc[3] + bb.w, 0.f));
        *(uint2*)&H1[row * HLD + 16 * t + 4 * q] = st;
    }
    __syncthreads();

    // ---- phase 3: GEMM2 (128->64). wave w: tile t2 = w>>1, same nh/row.
    const int t2 = w >> 1;
    floatx4 a2 = {0.f, 0.f, 0.f, 0.f};
#pragma unroll
    for (int s2 = 0; s2 < 8; ++s2) {
        half4v b2w = lda4(&H1[row * HLD + 16 * s2 + 4 * q]);
        a2 = MFMA16(lda4(&Wt2[(size_t)(16 * t2 + nd) * 128 + 16 * s2 + 4 * q]), b2w, a2);
    }
    const int onode = wbase + row;
    if (onode < N) {
        float dvn = dinv[onode];
        uint2 st;
        st.x = pk2i(a2[0] * dvn, a2[1] * dvn);
        st.y = pk2i(a2[2] * dvn, a2[3] * dvn);
        *(uint2*)&out[(size_t)onode * 64 + 16 * t2 + 4 * q] = st;
    }
}

// ===========================================================================
// fg_kernel (layers 3+4) — VALU GEMM (hidden under gather), slice-phased.
// ===========================================================================
template <int OUT, int NPB, bool GBR, int GMODE>
__launch_bounds__(NPB * 16)
static __global__ void fg_kernel(const __half* __restrict__ hs, const int* __restrict__ rowptr,
                                 const int* __restrict__ col, const float* __restrict__ dinv,
                                 const int* __restrict__ sliceoff,
                                 const float* __restrict__ gbias, const float* __restrict__ W,
                                 const float* __restrict__ obias, __half* __restrict__ out, int N) {
    constexpr int K = 64;
    constexpr int NT = NPB * 16;
    constexpr int CPT = OUT / 16;          // 4 / 2
    __shared__ int Wl2[(K / 2) * OUT];
    const int tid = threadIdx.x;

    for (int i = tid; i < (K / 2) * OUT; i += NT) {
        int c = i % OUT;
        int kk2 = i / OUT;
        Wl2[i] = pk2i(W[(size_t)(2 * kk2) * OUT + c], W[(size_t)(2 * kk2 + 1) * OUT + c]);
    }
    __syncthreads();

    const int lane = tid & 15;
    const int node = blockIdx.x * NPB + (tid >> 4);
    if (node >= N) return;

    float dv;
    float4 r = gather64s<GBR>(hs, rowptr, col, dinv, gbias, sliceoff,
                              node, lane, blockIdx.x & 7, dv);

    int ip0 = pk2i(r.x, r.y);
    int ip1 = pk2i(r.z, r.w);

    float oacc[CPT];
#pragma unroll
    for (int c = 0; c < CPT; ++c) oacc[c] = 0.f;

#pragma unroll
    for (int src = 0; src < 16; ++src) {
        half2v a0 = i2h(__shfl(ip0, src, 16));
        half2v a1 = i2h(__shfl(ip1, src, 16));
        if (CPT >= 4) {
#pragma unroll
            for (int c = 0; c < CPT / 4; ++c) {
                int4 w0 = *(int4*)&Wl2[(2 * src) * OUT + c * 64 + lane * 4];
                int4 w1 = *(int4*)&Wl2[(2 * src + 1) * OUT + c * 64 + lane * 4];
                oacc[c * 4 + 0] = FDOT2(a0, i2h(w0.x), oacc[c * 4 + 0]);
                oacc[c * 4 + 1] = FDOT2(a0, i2h(w0.y), oacc[c * 4 + 1]);
                oacc[c * 4 + 2] = FDOT2(a0, i2h(w0.z), oacc[c * 4 + 2]);
                oacc[c * 4 + 3] = FDOT2(a0, i2h(w0.w), oacc[c * 4 + 3]);
                oacc[c * 4 + 0] = FDOT2(a1, i2h(w1.x), oacc[c * 4 + 0]);
                oacc[c * 4 + 1] = FDOT2(a1, i2h(w1.y), oacc[c * 4 + 1]);
                oacc[c * 4 + 2] = FDOT2(a1, i2h(w1.z), oacc[c * 4 + 2]);
                oacc[c * 4 + 3] = FDOT2(a1, i2h(w1.w), oacc[c * 4 + 3]);
            }
        } else {
            int2 w0 = *(int2*)&Wl2[(2 * src) * OUT + lane * 2];
            int2 w1 = *(int2*)&Wl2[(2 * src + 1) * OUT + lane * 2];
            oacc[0] = FDOT2(a0, i2h(w0.x), oacc[0]);
            oacc[1] = FDOT2(a0, i2h(w0.y), oacc[1]);
            oacc[0] = FDOT2(a1, i2h(w1.x), oacc[0]);
            oacc[1] = FDOT2(a1, i2h(w1.y), oacc[1]);
        }
    }

    if (CPT >= 4) {
#pragma unroll
        for (int c = 0; c < CPT / 4; ++c) {
            float4 o;
            o.x = oacc[c * 4 + 0] * dv;
            o.y = oacc[c * 4 + 1] * dv;
            o.z = oacc[c * 4 + 2] * dv;
            o.w = oacc[c * 4 + 3] * dv;
            f4toh4(&out[(size_t)node * OUT + c * 64 + lane * 4], o);
        }
    } else {
        *(__half2*)&out[(size_t)node * OUT + lane * 2] =
            __floats2half2_rn(oacc[0] * dv, oacc[1] * dv);
    }
}

// Fused gather(32,fp16) + b4/relu + dot(Wfc) + segment-mean pooling.
// Gather: slice-phased two ranges, uniform batched chunks, sc0 loads.
__launch_bounds__(256)
static __global__ void fg4_kernel(const __half* __restrict__ hs, const int* __restrict__ rowptr,
                                  const int* __restrict__ col, const float* __restrict__ dinv,
                                  const int* __restrict__ sliceoff,
                                  const float* __restrict__ b4, const float* __restrict__ Wfc,
                                  const int* __restrict__ batch, float* __restrict__ psum,
                                  int* __restrict__ pcnt, int N) {
    constexpr int K = 32;
    __shared__ float wl[32];
    __shared__ float gsum[64];
    __shared__ int gcnt[64];
    __shared__ int sbase;
    const int tid = threadIdx.x;
    if (tid < 32) wl[tid] = Wfc[tid];
    if (tid < 64) { gsum[tid] = 0.f; gcnt[tid] = 0; }
    if (tid == 0) {
        int bi = (int)blockIdx.x * 32;
        if (bi > N - 1) bi = N - 1;
        sbase = batch[bi];
    }
    __syncthreads();

    const int lane = tid & 7;
    const int li = tid >> 3;
    const int node = blockIdx.x * 32 + li;
    const int phase = blockIdx.x & 7;
    float val = 0.f;
    if (node < N) {
        const int beg = rowptr[node];
        const int end = rowptr[node + 1];
        const int split = sliceoff[(size_t)node * 8 + phase];
        union U2 { uint2 u; __half2 h[2]; };
        union UQ { uint64_t q; __half2 h[2]; };
        U2 cv;
        cv.u = *(const uint2*)&hs[(size_t)node * K + lane * 4];
        __half2 a0 = cv.h[0], a1 = cv.h[1];
        const __half2 z2 = __float2half2_rn(0.f);
        __half2 b0h = z2, b1h = z2;

        int lo = split, hi = end;
#pragma unroll 1
        for (int pass = 0; pass < 2; ++pass) {
            int myc = (lo + lane < hi) ? col[lo + lane] : 0;
            for (int e = lo; e < hi; e += 8) {
                const int rem = hi - e;
                int nmyc = 0;
                if (e + 8 + lane < hi) nmyc = col[e + 8 + lane];
                uint64_t v[8];
#pragma unroll
                for (int j = 0; j < 8; ++j) {
                    int s = __shfl(myc, j, 8);
                    ld8_sc0(v[j], &hs[(size_t)s * K + lane * 4]);
                }
                vm_wait0();
#pragma unroll
                for (int j = 0; j < 8; j += 2) {
                    UQ x0, x1;
                    x0.q = (j < rem) ? v[j] : 0ull;
                    x1.q = (j + 1 < rem) ? v[j + 1] : 0ull;
                    a0 = __hadd2(a0, x0.h[0]); a1 = __hadd2(a1, x0.h[1]);
                    b0h = __hadd2(b0h, x1.h[0]); b1h = __hadd2(b1h, x1.h[1]);
                }
                myc = nmyc;
            }
            lo = beg; hi = split;
        }
        float2 fa0 = __half22float2(a0), fa1 = __half22float2(a1);
        float2 fb0 = __half22float2(b0h), fb1 = __half22float2(b1h);
        float dv = dinv[node];
        float4 bv = *(const float4*)&b4[lane * 4];
        float4 h;
        h.x = fmaxf((fa0.x + fb0.x) * dv + bv.x, 0.f);
        h.y = fmaxf((fa0.y + fb0.y) * dv + bv.y, 0.f);
        h.z = fmaxf((fa1.x + fb1.x) * dv + bv.z, 0.f);
        h.w = fmaxf((fa1.y + fb1.y) * dv + bv.w, 0.f);
        val = h.x * wl[lane * 4 + 0] + h.y * wl[lane * 4 + 1] +
              h.z * wl[lane * 4 + 2] + h.w * wl[lane * 4 + 3];
    }
    val += __shfl_xor(val, 1, 8);
    val += __shfl_xor(val, 2, 8);
    val += __shfl_xor(val, 4, 8);
    if (node < N && lane == 0) {
        int g = batch[node];
        int rel = g - sbase;
        if ((unsigned)rel < 64u) {
            atomicAdd(&gsum[rel], val);
            atomicAdd(&gcnt[rel], 1);
        } else {
            unsafeAtomicAdd(&psum[g], val);
            atomicAdd(&pcnt[g], 1);
        }
    }
    __syncthreads();
    if (tid < 64 && gcnt[tid] > 0) {
        unsafeAtomicAdd(&psum[sbase + tid], gsum[tid]);
        atomicAdd(&pcnt[sbase + tid], gcnt[tid]);
    }
}

static __global__ void final_kernel(const float* __restrict__ psum, const int* __restrict__ pcnt,
                                    const float* __restrict__ bfc, float* __restrict__ out, int G) {
    int t = threadIdx.x;
    if (t < G) {
        float c = (float)pcnt[t];
        out[t] = psum[t] / fmaxf(c, 1.f) + bfc[0];
    }
}

extern "C" void kernel_launch(void* const* d_in, const int* in_sizes, int n_in,
                              void* d_out, int out_size, void* d_ws, size_t ws_size,
                              hipStream_t stream) {
    const float* x    = (const float*)d_in[0];
    const int*   ei   = (const int*)d_in[1];
    const int*   batch= (const int*)d_in[2];
    const float* W1   = (const float*)d_in[4];
    const float* b1   = (const float*)d_in[5];
    const float* W2   = (const float*)d_in[6];
    const float* b2   = (const float*)d_in[7];
    const float* W3   = (const float*)d_in[8];
    const float* b3   = (const float*)d_in[9];
    const float* W4   = (const float*)d_in[10];
    const float* b4   = (const float*)d_in[11];
    const float* Wfc  = (const float*)d_in[12];
    const float* bfc  = (const float*)d_in[13];
    float* out = (float*)d_out;

    const int N = in_sizes[0] / 64;
    const int E = in_sizes[1] / 2;
    const int G = out_size;
    const int* srcp = ei;
    const int* dstp = ei + E;
    const int NB = (N + BKT_SZ - 1) >> BKT_LG;   // 391 for N=100k
    const int Ns = (N + 7) / 8;                  // slice width (8 slices)

    // workspace layout (float-sized slots)
    float* wsf = (float*)d_ws;
    const size_t Npad = ((size_t)N + 1023) / 1024 * 1024;
    const size_t Epad = ((size_t)E + 1023) / 1024 * 1024;
    float*    dinv   = wsf;                            // Npad
    int*      rowptr = (int*)(wsf + Npad);             // Npad + 1024
    int*      col    = (int*)(wsf + 2 * Npad + 1024);  // Epad
    unsigned* binned = (unsigned*)((float*)col + Epad);// Epad
    int*      bcnt   = (int*)((float*)binned + Epad);  // 512
    int*      base   = bcnt + 512;                     // 512
    int*      bfill  = base + 512;                     // 512
    float*    psum   = (float*)(bfill + 512);          // 256
    int*      pcnt   = (int*)(psum + 256);             // 256
    __half*   T1h    = (__half*)(psum + 1024);         // Npad*64 halves
    __half*   T2h    = (__half*)((float*)T1h + Npad * 32); // Npad*64 halves
    int*      sliceoff = (int*)((float*)T2h + Npad * 32);  // N*8 ints
    // packed-transposed fp16 W1/W2 alias the (dead-after-group) binned region
    __half*   Wth    = (__half*)binned;                // 16384 halves
    const __half* Wt1 = Wth;
    const __half* Wt2 = Wth + 8192;

    const int gN16 = (N * 16 + 255) / 256;
    const int nbin = (E + BIN_CHUNK - 1) / BIN_CHUNK;
    const int gBH  = (E + 2047) / 2048;
    const int gFGM1 = (N + 31) / 32;  // 512 threads, 32 nodes, 8 waves
    const int gFG  = (N + 15) / 16;   // 256 threads, 16 nodes
    const int gFG4 = (N + 31) / 32;

    hipMemsetAsync(bcnt, 0, 512 * sizeof(int), stream);
    hipMemsetAsync(psum, 0, 512 * sizeof(float), stream);

    // ---- CSR build (by dst, col = src, slice-sorted within node) + dinv
    bhist_kernel<<<gBH, 256, 0, stream>>>(dstp, bcnt, E, NB);
    bscan_kernel<<<1, 512, 0, stream>>>(bcnt, base, bfill, NB, E);
    bin_kernel<<<nbin, 256, 0, stream>>>(srcp, dstp, bfill, binned, E, NB);
    group_kernel<<<NB, 256, 0, stream>>>(binned, base, rowptr, col, dinv, sliceoff, Ns, N, E);

    // ---- weight prepack (after group: overwrites binned) + input scale
    wprep12_kernel<<<64, 256, 0, stream>>>(W1, W2, Wth);
    scale_kernel<<<gN16, 256, 0, stream>>>(x, dinv, T1h, N);

    // ---- layers 1+2: gather -> LDS -> MFMA GEMM1(+b1,relu) -> MFMA GEMM2(*dinv) -> T2h
    fgmm1_kernel<<<gFGM1, 512, 0, stream>>>(T1h, rowptr, col, dinv, sliceoff, Wt1, Wt2, b1, T2h, N);

    // ---- layer 3: fused gather2(+b2,relu) + GEMM3(64->64, *dinv) -> T1h
    fg_kernel<64, 16, true, 1><<<gFG, 256, 0, stream>>>(T2h, rowptr, col, dinv, sliceoff, b2, W3, nullptr, T1h, N);

    // ---- layer 4: fused gather3(+b3,relu) + GEMM4(64->32, *dinv) -> T2h
    fg_kernel<32, 16, true, 1><<<gFG, 256, 0, stream>>>(T1h, rowptr, col, dinv, sliceoff, b3, W4, nullptr, T2h, N);

    // ---- fused gather4(+b4,relu) + fc-dot + pooled segment sums
    fg4_kernel<<<gFG4, 256, 0, stream>>>(T2h, rowptr, col, dinv, sliceoff, b4, Wfc, batch, psum, pcnt, N);

    // ---- final mean + bias
    final_kernel<<<1, 256, 0, stream>>>(psum, pcnt, bfc, out, G);
}

// Round 10
// 320.594 us; speedup vs baseline: 1.1149x; 1.1149x over previous
//
#include <hip/hip_runtime.h>
#include <hip/hip_fp16.h>
#include <cstdint>
#include <cstddef>

// ---------------------------------------------------------------------------
// GCN regression. Round 28: fp8(e4m3) gather tables -> 1 cache line per edge.
// R27 post-mortem: slicing regressed; FETCH(82-84MB) == per-XCD compulsory
// floor (0.86*12.8MB*8 = 88MB) and the miss-service rate is pinned at
// ~0.9 lines/cyc/XCD across every structure (R18,R22-R27). Only lever left:
// bytes/edge. All gathered tables now fp8: 64-dim row = 64B = 1 line (was 2).
// Gather: HW v_cvt_pk_f32_fp8 decode + fp32 accumulation (better than old
// fp16 tree). GEMMs/weights/LDS unchanged fp16. Slicing reverted to R26 CSR.
// Accuracy gamble, made explicit: per-node ~3% rel fp8 noise mean-pools over
// ~390 nodes -> expected absmax ~1e-3..1e-2. Fail => revert + roofline.
// ---------------------------------------------------------------------------

#define BKT_LG 8
#define BKT_SZ 256
#define BIN_CHUNK 2048

#define XLD 68    // X row stride in halves (64 + 4 pad)
#define HLD 132   // H1 row stride in halves (128 + 4 pad)

using half2v = decltype(__builtin_amdgcn_cvt_pkrtz(0.0f, 0.0f));
typedef _Float16 half4v __attribute__((ext_vector_type(4)));
typedef float floatx4 __attribute__((ext_vector_type(4)));
typedef float floatx2 __attribute__((ext_vector_type(2)));

#define MFMA16(a, b, c) __builtin_amdgcn_mfma_f32_16x16x16f16((a), (b), (c), 0, 0, 0)

#if __has_builtin(__builtin_amdgcn_fdot2)
#define FDOT2(a, b, c) __builtin_amdgcn_fdot2((a), (b), (c), false)
#else
__device__ __forceinline__ float fdot2_emul(half2v a, half2v b, float c) {
    return c + (float)a[0] * (float)b[0] + (float)a[1] * (float)b[1];
}
#define FDOT2(a, b, c) fdot2_emul((a), (b), (c))
#endif

#if __has_builtin(__builtin_amdgcn_cvt_pk_f32_fp8) && __has_builtin(__builtin_amdgcn_cvt_pk_fp8_f32)
#define HAS_HW_FP8 1
#endif

// ---- fp8 e4m3 <-> f32 (HW path on gfx950; SW fallback for safety) ----
#ifndef HAS_HW_FP8
__device__ __forceinline__ float fp8_to_f32_sw(uint32_t b) {
    uint32_t s = (b >> 7) & 1u, e = (b >> 3) & 0xFu, m = b & 7u;
    float v = (e == 0) ? ldexpf((float)m, -9) : ldexpf((float)(8u + m), (int)e - 10);
    return s ? -v : v;
}
__device__ __forceinline__ uint32_t f32_to_fp8_sw(float f) {
    uint32_t s = (f < 0.f) ? 0x80u : 0u;
    float a = fabsf(f);
    if (!(a > 0.f)) return s;
    if (a > 448.f) a = 448.f;
    int e; frexpf(a, &e);          // a = fr*2^e, fr in [0.5,1)
    int be = e + 6;                // biased exponent
    if (be <= 0) {                 // subnormal: m = round(a*2^9)
        int m = (int)rintf(ldexpf(a, 9));
        if (m >= 8) return s | 0x08u;
        return s | (uint32_t)m;
    }
    int m = (int)rintf(ldexpf(a, 3 - (e - 1))) - 8;   // [8,16) -> m in [0,8]
    if (m >= 8) { m = 0; be += 1; }
    if (be >= 16) { be = 15; m = 6; }                  // clamp at 448 (e15m6)
    return s | ((uint32_t)be << 3) | (uint32_t)m;
}
#endif

__device__ __forceinline__ void fp8x4_f32(uint32_t v, float& f0, float& f1, float& f2, float& f3) {
#ifdef HAS_HW_FP8
    floatx2 lo = __builtin_amdgcn_cvt_pk_f32_fp8((int)v, false);
    floatx2 hi = __builtin_amdgcn_cvt_pk_f32_fp8((int)v, true);
    f0 = lo[0]; f1 = lo[1]; f2 = hi[0]; f3 = hi[1];
#else
    f0 = fp8_to_f32_sw(v & 0xffu);
    f1 = fp8_to_f32_sw((v >> 8) & 0xffu);
    f2 = fp8_to_f32_sw((v >> 16) & 0xffu);
    f3 = fp8_to_f32_sw(v >> 24);
#endif
}
__device__ __forceinline__ uint32_t f32_fp8x4(float a, float b, float c, float d) {
#ifdef HAS_HW_FP8
    int r = 0;
    r = __builtin_amdgcn_cvt_pk_fp8_f32(a, b, r, false);
    r = __builtin_amdgcn_cvt_pk_fp8_f32(c, d, r, true);
    return (uint32_t)r;
#else
    return f32_to_fp8_sw(a) | (f32_to_fp8_sw(b) << 8) |
           (f32_to_fp8_sw(c) << 16) | (f32_to_fp8_sw(d) << 24);
#endif
}
__device__ __forceinline__ uint32_t f32_fp8x2(float a, float b) {
#ifdef HAS_HW_FP8
    return (uint32_t)__builtin_amdgcn_cvt_pk_fp8_f32(a, b, 0, false);
#else
    return f32_to_fp8_sw(a) | (f32_to_fp8_sw(b) << 8);
#endif
}

__device__ __forceinline__ int h2i(half2v h) { union { int i; half2v h; } u; u.h = h; return u.i; }
__device__ __forceinline__ half2v i2h(int i) { union { int i; half2v h; } u; u.i = i; return u.h; }
__device__ __forceinline__ int pk2i(float a, float b) { return h2i(__builtin_amdgcn_cvt_pkrtz(a, b)); }

__device__ __forceinline__ half4v lda4(const __half* p) {
    union { uint2 u; half4v h; } w;
    w.u = *(const uint2*)p;
    return w.h;
}

// L1-bypass 4B load: issue only. NOT READY until a vmcnt wait.
__device__ __forceinline__ void ld4_sc0(uint32_t& r, const void* p) {
    asm volatile("global_load_dword %0, %1, off sc0" : "=&v"(r) : "v"(p));
}
__device__ __forceinline__ void vm_wait0() {
    asm volatile("s_waitcnt vmcnt(0)" ::: "memory");
    __builtin_amdgcn_sched_barrier(0);
}

// ---- bucket histogram: bcnt[b] = #edges with dst in bucket b
static __global__ void bhist_kernel(const int* __restrict__ dst, int* __restrict__ bcnt,
                                    int E, int NB) {
    __shared__ int h[512];
    for (int i = threadIdx.x; i < NB; i += 256) h[i] = 0;
    __syncthreads();
    for (int t = blockIdx.x * 256 + threadIdx.x; t < E; t += gridDim.x * 256)
        atomicAdd(&h[dst[t] >> BKT_LG], 1);
    __syncthreads();
    for (int i = threadIdx.x; i < NB; i += 256)
        if (h[i]) atomicAdd(&bcnt[i], h[i]);
}

// ---- exclusive scan of bcnt -> base (NB+1), bfill = base  (single block, 512)
static __global__ void bscan_kernel(const int* __restrict__ bcnt, int* __restrict__ base,
                                    int* __restrict__ bfill, int NB, int E) {
    __shared__ int s[512];
    int t = threadIdx.x;
    int v = (t < NB) ? bcnt[t] : 0;
    s[t] = v;
    __syncthreads();
    for (int off = 1; off < 512; off <<= 1) {
        int u = (t >= off) ? s[t - off] : 0;
        __syncthreads();
        s[t] += u;
        __syncthreads();
    }
    if (t < NB) { base[t] = s[t] - v; bfill[t] = s[t] - v; }
    if (t == 0) base[NB] = E;
}

// ---- bin edges into bucket-contiguous runs
__launch_bounds__(256)
static __global__ void bin_kernel(const int* __restrict__ src, const int* __restrict__ dst,
                                  int* __restrict__ bfill, unsigned* __restrict__ binned,
                                  int E, int NB) {
    __shared__ int h[512];
    __shared__ int res[512];
    const int beg = blockIdx.x * BIN_CHUNK;
    const int ce = min(BIN_CHUNK, E - beg);
    for (int i = threadIdx.x; i < NB; i += 256) h[i] = 0;
    __syncthreads();
    for (int i = threadIdx.x; i < ce; i += 256)
        atomicAdd(&h[dst[beg + i] >> BKT_LG], 1);
    __syncthreads();
    for (int i = threadIdx.x; i < NB; i += 256) {
        res[i] = h[i] ? atomicAdd(&bfill[i], h[i]) : 0;
        h[i] = 0;
    }
    __syncthreads();
    for (int i = threadIdx.x; i < ce; i += 256) {
        int d = dst[beg + i];
        int b = d >> BKT_LG;
        int p = res[b] + atomicAdd(&h[b], 1);
        binned[p] = ((unsigned)src[beg + i] << BKT_LG) | (unsigned)(d & (BKT_SZ - 1));
    }
}

// ---- per-bucket (256 nodes): count, scan, emit rowptr/dinv, group col (R26)
__launch_bounds__(256)
static __global__ void group_kernel(const unsigned* __restrict__ binned, const int* __restrict__ base,
                                    int* __restrict__ rowptr, int* __restrict__ col,
                                    float* __restrict__ dinv, int N, int E) {
    __shared__ int cnt[BKT_SZ];
    __shared__ int ex[BKT_SZ];
    __shared__ int ps[256];
    const int tid = threadIdx.x;
    const int b = blockIdx.x;
    const int node0 = b << BKT_LG;
    const int nn = min(BKT_SZ, N - node0);
    const int beg = base[b], end = base[b + 1];

    cnt[tid] = 0;
    __syncthreads();
    for (int i = beg + tid; i < end; i += 256)
        atomicAdd(&cnt[binned[i] & (BKT_SZ - 1)], 1);
    __syncthreads();

    int c = cnt[tid];
    ps[tid] = c;
    __syncthreads();
    for (int off = 1; off < 256; off <<= 1) {
        int u = (tid >= off) ? ps[tid - off] : 0;
        __syncthreads();
        ps[tid] += u;
        __syncthreads();
    }
    int excl = ps[tid] - c;
    ex[tid] = excl;
    __syncthreads();

    if (tid < nn) {
        rowptr[node0 + tid] = beg + excl;
        dinv[node0 + tid] = rsqrtf((float)c + 1.0f);
    }
    if (b == 0 && tid == 0) rowptr[N] = E;
    __syncthreads();

    for (int i = beg + tid; i < end; i += 256) {
        unsigned v = binned[i];
        int dl = v & (BKT_SZ - 1);
        int p = atomicAdd(&ex[dl], 1);
        col[beg + p] = (int)(v >> BKT_LG);
    }
}

// o[row] = fp8( x[row] * dinv[row] ), dim 64
static __global__ void scale_kernel(const float* __restrict__ x, const float* __restrict__ dinv,
                                    uint8_t* __restrict__ o, int N) {
    int t = blockIdx.x * 256 + threadIdx.x;
    if (t >= N * 16) return;
    int row = t >> 4;
    int c = (t & 15) * 4;
    float d = dinv[row];
    float4 v = *(const float4*)&x[(size_t)row * 64 + c];
    *(uint32_t*)&o[(size_t)row * 64 + c] = f32_fp8x4(v.x * d, v.y * d, v.z * d, v.w * d);
}

// ---- prepack W1/W2: fp16 transposed. Wt1 [128][64] @0, Wt2 [64][128] @8192.
static __global__ void wprep12_kernel(const float* __restrict__ W1, const float* __restrict__ W2,
                                      __half* __restrict__ Wt) {
    int i = blockIdx.x * 256 + threadIdx.x;
    if (i < 8192) {
        int o = i >> 6, k = i & 63;
        Wt[i] = __float2half(W1[(size_t)k * 128 + o]);
    } else if (i < 16384) {
        int j = i - 8192, o = j >> 7, k = j & 127;
        Wt[i] = __float2half(W2[(size_t)k * 64 + o]);
    }
}

// ===========================================================================
// 16-lane/node gather from fp8 table (64B rows = 1 line/edge).
// Uniform 8-edge batched chunks, sc0 dword loads, fp32 accumulation.
// ===========================================================================
template <bool GBR>
__device__ __forceinline__ float4 gather64f8(const uint8_t* __restrict__ hs,
                                             const int* __restrict__ rowptr,
                                             const int* __restrict__ col,
                                             const float* __restrict__ dinv,
                                             const float* __restrict__ gbias,
                                             int node, int lane, float& dv) {
    const int beg = rowptr[node];
    const int end = rowptr[node + 1];
    const int lane8 = lane & 7;
    float a0, a1, a2, a3;
    {   // self loop
        uint32_t sv = *(const uint32_t*)&hs[(size_t)node * 64 + lane * 4];
        fp8x4_f32(sv, a0, a1, a2, a3);
    }
    int myc = (beg + lane8 < end) ? col[beg + lane8] : 0;
    for (int e = beg; e < end; e += 8) {
        const int rem = end - e;                       // uniform per 16-lane group
        int nmyc = 0;
        if (e + 8 + lane8 < end) nmyc = col[e + 8 + lane8];   // prefetch next cols
        uint32_t v[8];
#pragma unroll
        for (int j = 0; j < 8; ++j) {
            int s = __shfl(myc, j, 16);                // clamped col: always safe
            ld4_sc0(v[j], &hs[(size_t)s * 64 + lane * 4]);
        }
        vm_wait0();
#pragma unroll
        for (int j = 0; j < 8; ++j) {
            uint32_t x = (j < rem) ? v[j] : 0u;        // fp8 0x00 == 0.0
            float f0, f1, f2, f3;
            fp8x4_f32(x, f0, f1, f2, f3);
            a0 += f0; a1 += f1; a2 += f2; a3 += f3;
        }
        myc = nmyc;
    }
    dv = dinv[node];
    float4 r;
    r.x = a0 * dv; r.y = a1 * dv; r.z = a2 * dv; r.w = a3 * dv;
    if (GBR) {
        float4 bv = *(const float4*)&gbias[lane * 4];
        r.x = fmaxf(r.x + bv.x, 0.f);
        r.y = fmaxf(r.y + bv.y, 0.f);
        r.z = fmaxf(r.z + bv.z, 0.f);
        r.w = fmaxf(r.w + bv.w, 0.f);
    }
    return r;
}

// ===========================================================================
// fgmm1: fp8 gather -> LDS X (fp16) -> MFMA GEMM1(+b1,relu) -> LDS H1
//        -> MFMA GEMM2 -> *dinv -> fp8 out.  512 threads = 32 nodes, 8 waves.
// ===========================================================================
__launch_bounds__(512)
static __global__ void fgmm1_kernel(const uint8_t* __restrict__ hs, const int* __restrict__ rowptr,
                                    const int* __restrict__ col, const float* __restrict__ dinv,
                                    const __half* __restrict__ Wt1, const __half* __restrict__ Wt2,
                                    const float* __restrict__ b1, uint8_t* __restrict__ out, int N) {
    __shared__ __align__(16) __half X[32 * XLD];    // 4352 B
    __shared__ __align__(16) __half H1[32 * HLD];   // 8448 B
    const int tid = threadIdx.x;
    const int lane16 = tid & 15;
    const int nodei = tid >> 4;            // 0..31
    const int wbase = blockIdx.x * 32;

    // ---- phase 1: gather, pack fp16, stage in LDS ----
    float dvg = 0.f;
    float4 r = make_float4(0.f, 0.f, 0.f, 0.f);
    if (wbase + nodei < N)
        r = gather64f8<false>(hs, rowptr, col, dinv, nullptr, wbase + nodei, lane16, dvg);
    uint2 xp;
    xp.x = pk2i(r.x, r.y);
    xp.y = pk2i(r.z, r.w);
    *(uint2*)&X[nodei * XLD + 4 * lane16] = xp;
    __syncthreads();

    // ---- phase 2: GEMM1 (64->128) as MFMA tiles. wave w: nh=w&1, t in {w>>1, (w>>1)+4}
    const int w = tid >> 6;
    const int l = tid & 63;
    const int nd = l & 15;
    const int q = l >> 4;
    const int nh = w & 1;
    const int row = nh * 16 + nd;          // node index in block (B/D column)

    half4v bw[4];
#pragma unroll
    for (int s = 0; s < 4; ++s)
        bw[s] = lda4(&X[row * XLD + 16 * s + 4 * q]);

#pragma unroll
    for (int tt = 0; tt < 2; ++tt) {
        const int t = (w >> 1) + tt * 4;
        floatx4 acc = {0.f, 0.f, 0.f, 0.f};
#pragma unroll
        for (int s = 0; s < 4; ++s)
            acc = MFMA16(lda4(&Wt1[(size_t)(16 * t + nd) * 64 + 16 * s + 4 * q]), bw[s], acc);
        float4 bb = *(const float4*)&b1[16 * t + 4 * q];
        uint2 st;
        st.x = pk2i(fmaxf(acc[0] + bb.x, 0.f), fmaxf(acc[1] + bb.y, 0.f));
        st.y = pk2i(fmaxf(acc[2] + bb.z, 0.f), fmaxf(acc[3] + bb.w, 0.f));
        *(uint2*)&H1[row * HLD + 16 * t + 4 * q] = st;
    }
    __syncthreads();

    // ---- phase 3: GEMM2 (128->64). wave w: tile t2 = w>>1, same nh/row.
    const int t2 = w >> 1;
    floatx4 a2 = {0.f, 0.f, 0.f, 0.f};
#pragma unroll
    for (int s2 = 0; s2 < 8; ++s2) {
        half4v b2w = lda4(&H1[row * HLD + 16 * s2 + 4 * q]);
        a2 = MFMA16(lda4(&Wt2[(size_t)(16 * t2 + nd) * 128 + 16 * s2 + 4 * q]), b2w, a2);
    }
    const int onode = wbase + row;
    if (onode < N) {
        float dvn = dinv[onode];
        *(uint32_t*)&out[(size_t)onode * 64 + 16 * t2 + 4 * q] =
            f32_fp8x4(a2[0] * dvn, a2[1] * dvn, a2[2] * dvn, a2[3] * dvn);
    }
}

// ===========================================================================
// fg_kernel (layers 3+4) — fp8 gather + VALU GEMM (hidden), fp8 out.
// ===========================================================================
template <int OUT, int NPB, bool GBR, int GMODE>
__launch_bounds__(NPB * 16)
static __global__ void fg_kernel(const uint8_t* __restrict__ hs, const int* __restrict__ rowptr,
                                 const int* __restrict__ col, const float* __restrict__ dinv,
                                 const float* __restrict__ gbias, const float* __restrict__ W,
                                 const float* __restrict__ obias, uint8_t* __restrict__ out, int N) {
    constexpr int K = 64;
    constexpr int NT = NPB * 16;
    constexpr int CPT = OUT / 16;          // 4 / 2
    __shared__ int Wl2[(K / 2) * OUT];
    const int tid = threadIdx.x;

    for (int i = tid; i < (K / 2) * OUT; i += NT) {
        int c = i % OUT;
        int kk2 = i / OUT;
        Wl2[i] = pk2i(W[(size_t)(2 * kk2) * OUT + c], W[(size_t)(2 * kk2 + 1) * OUT + c]);
    }
    __syncthreads();

    const int lane = tid & 15;
    const int node = blockIdx.x * NPB + (tid >> 4);
    if (node >= N) return;

    float dv;
    float4 r = gather64f8<GBR>(hs, rowptr, col, dinv, gbias, node, lane, dv);

    int ip0 = pk2i(r.x, r.y);
    int ip1 = pk2i(r.z, r.w);

    float oacc[CPT];
#pragma unroll
    for (int c = 0; c < CPT; ++c) oacc[c] = 0.f;

#pragma unroll
    for (int src = 0; src < 16; ++src) {
        half2v a0 = i2h(__shfl(ip0, src, 16));
        half2v a1 = i2h(__shfl(ip1, src, 16));
        if (CPT >= 4) {
#pragma unroll
            for (int c = 0; c < CPT / 4; ++c) {
                int4 w0 = *(int4*)&Wl2[(2 * src) * OUT + c * 64 + lane * 4];
                int4 w1 = *(int4*)&Wl2[(2 * src + 1) * OUT + c * 64 + lane * 4];
                oacc[c * 4 + 0] = FDOT2(a0, i2h(w0.x), oacc[c * 4 + 0]);
                oacc[c * 4 + 1] = FDOT2(a0, i2h(w0.y), oacc[c * 4 + 1]);
                oacc[c * 4 + 2] = FDOT2(a0, i2h(w0.z), oacc[c * 4 + 2]);
                oacc[c * 4 + 3] = FDOT2(a0, i2h(w0.w), oacc[c * 4 + 3]);
                oacc[c * 4 + 0] = FDOT2(a1, i2h(w1.x), oacc[c * 4 + 0]);
                oacc[c * 4 + 1] = FDOT2(a1, i2h(w1.y), oacc[c * 4 + 1]);
                oacc[c * 4 + 2] = FDOT2(a1, i2h(w1.z), oacc[c * 4 + 2]);
                oacc[c * 4 + 3] = FDOT2(a1, i2h(w1.w), oacc[c * 4 + 3]);
            }
        } else {
            int2 w0 = *(int2*)&Wl2[(2 * src) * OUT + lane * 2];
            int2 w1 = *(int2*)&Wl2[(2 * src + 1) * OUT + lane * 2];
            oacc[0] = FDOT2(a0, i2h(w0.x), oacc[0]);
            oacc[1] = FDOT2(a0, i2h(w0.y), oacc[1]);
            oacc[0] = FDOT2(a1, i2h(w1.x), oacc[0]);
            oacc[1] = FDOT2(a1, i2h(w1.y), oacc[1]);
        }
    }

    if (CPT >= 4) {
        *(uint32_t*)&out[(size_t)node * OUT + lane * 4] =
            f32_fp8x4(oacc[0] * dv, oacc[1] * dv, oacc[2] * dv, oacc[3] * dv);
    } else {
        *(uint16_t*)&out[(size_t)node * OUT + lane * 2] =
            (uint16_t)(f32_fp8x2(oacc[0] * dv, oacc[1] * dv) & 0xffffu);
    }
}

// Fused gather(32-dim fp8) + b4/relu + dot(Wfc) + segment-mean pooling.
__launch_bounds__(256)
static __global__ void fg4_kernel(const uint8_t* __restrict__ hs, const int* __restrict__ rowptr,
                                  const int* __restrict__ col, const float* __restrict__ dinv,
                                  const float* __restrict__ b4, const float* __restrict__ Wfc,
                                  const int* __restrict__ batch, float* __restrict__ psum,
                                  int* __restrict__ pcnt, int N) {
    __shared__ float wl[32];
    __shared__ float gsum[64];
    __shared__ int gcnt[64];
    __shared__ int sbase;
    const int tid = threadIdx.x;
    if (tid < 32) wl[tid] = Wfc[tid];
    if (tid < 64) { gsum[tid] = 0.f; gcnt[tid] = 0; }
    if (tid == 0) {
        int bi = (int)blockIdx.x * 32;
        if (bi > N - 1) bi = N - 1;
        sbase = batch[bi];
    }
    __syncthreads();

    const int lane = tid & 7;
    const int li = tid >> 3;
    const int node = blockIdx.x * 32 + li;
    float val = 0.f;
    if (node < N) {
        const int beg = rowptr[node];
        const int end = rowptr[node + 1];
        float a0, a1, a2, a3;
        {
            uint32_t sv = *(const uint32_t*)&hs[(size_t)node * 32 + lane * 4];
            fp8x4_f32(sv, a0, a1, a2, a3);
        }
        int myc = (beg + lane < end) ? col[beg + lane] : 0;
        for (int e = beg; e < end; e += 8) {
            const int rem = end - e;
            int nmyc = 0;
            if (e + 8 + lane < end) nmyc = col[e + 8 + lane];
            uint32_t v[8];
#pragma unroll
            for (int j = 0; j < 8; ++j) {
                int s = __shfl(myc, j, 8);
                ld4_sc0(v[j], &hs[(size_t)s * 32 + lane * 4]);
            }
            vm_wait0();
#pragma unroll
            for (int j = 0; j < 8; ++j) {
                uint32_t x = (j < rem) ? v[j] : 0u;
                float f0, f1, f2, f3;
                fp8x4_f32(x, f0, f1, f2, f3);
                a0 += f0; a1 += f1; a2 += f2; a3 += f3;
            }
            myc = nmyc;
        }
        float dv = dinv[node];
        float4 bv = *(const float4*)&b4[lane * 4];
        float h0 = fmaxf(a0 * dv + bv.x, 0.f);
        float h1 = fmaxf(a1 * dv + bv.y, 0.f);
        float h2 = fmaxf(a2 * dv + bv.z, 0.f);
        float h3 = fmaxf(a3 * dv + bv.w, 0.f);
        val = h0 * wl[lane * 4 + 0] + h1 * wl[lane * 4 + 1] +
              h2 * wl[lane * 4 + 2] + h3 * wl[lane * 4 + 3];
    }
    val += __shfl_xor(val, 1, 8);
    val += __shfl_xor(val, 2, 8);
    val += __shfl_xor(val, 4, 8);
    if (node < N && lane == 0) {
        int g = batch[node];
        int rel = g - sbase;
        if ((unsigned)rel < 64u) {
            atomicAdd(&gsum[rel], val);
            atomicAdd(&gcnt[rel], 1);
        } else {
            unsafeAtomicAdd(&psum[g], val);
            atomicAdd(&pcnt[g], 1);
        }
    }
    __syncthreads();
    if (tid < 64 && gcnt[tid] > 0) {
        unsafeAtomicAdd(&psum[sbase + tid], gsum[tid]);
        atomicAdd(&pcnt[sbase + tid], gcnt[tid]);
    }
}

static __global__ void final_kernel(const float* __restrict__ psum, const int* __restrict__ pcnt,
                                    const float* __restrict__ bfc, float* __restrict__ out, int G) {
    int t = threadIdx.x;
    if (t < G) {
        float c = (float)pcnt[t];
        out[t] = psum[t] / fmaxf(c, 1.f) + bfc[0];
    }
}

extern "C" void kernel_launch(void* const* d_in, const int* in_sizes, int n_in,
                              void* d_out, int out_size, void* d_ws, size_t ws_size,
                              hipStream_t stream) {
    const float* x    = (const float*)d_in[0];
    const int*   ei   = (const int*)d_in[1];
    const int*   batch= (const int*)d_in[2];
    const float* W1   = (const float*)d_in[4];
    const float* b1   = (const float*)d_in[5];
    const float* W2   = (const float*)d_in[6];
    const float* b2   = (const float*)d_in[7];
    const float* W3   = (const float*)d_in[8];
    const float* b3   = (const float*)d_in[9];
    const float* W4   = (const float*)d_in[10];
    const float* b4   = (const float*)d_in[11];
    const float* Wfc  = (const float*)d_in[12];
    const float* bfc  = (const float*)d_in[13];
    float* out = (float*)d_out;

    const int N = in_sizes[0] / 64;
    const int E = in_sizes[1] / 2;
    const int G = out_size;
    const int* srcp = ei;
    const int* dstp = ei + E;
    const int NB = (N + BKT_SZ - 1) >> BKT_LG;   // 391 for N=100k

    // workspace layout (float-sized slots)
    float* wsf = (float*)d_ws;
    const size_t Npad = ((size_t)N + 1023) / 1024 * 1024;
    const size_t Epad = ((size_t)E + 1023) / 1024 * 1024;
    float*    dinv   = wsf;                            // Npad
    int*      rowptr = (int*)(wsf + Npad);             // Npad + 1024
    int*      col    = (int*)(wsf + 2 * Npad + 1024);  // Epad
    unsigned* binned = (unsigned*)((float*)col + Epad);// Epad
    int*      bcnt   = (int*)((float*)binned + Epad);  // 512
    int*      base   = bcnt + 512;                     // 512
    int*      bfill  = base + 512;                     // 512
    float*    psum   = (float*)(bfill + 512);          // 256
    int*      pcnt   = (int*)(psum + 256);             // 256
    uint8_t*  T1f8   = (uint8_t*)(psum + 1024);        // Npad*64 bytes
    uint8_t*  T2f8   = T1f8 + Npad * 64;               // Npad*64 bytes
    // packed-transposed fp16 W1/W2 alias the (dead-after-group) binned region
    __half*   Wth    = (__half*)binned;                // 16384 halves
    const __half* Wt1 = Wth;
    const __half* Wt2 = Wth + 8192;

    const int gN16 = (N * 16 + 255) / 256;
    const int nbin = (E + BIN_CHUNK - 1) / BIN_CHUNK;
    const int gBH  = (E + 2047) / 2048;
    const int gFGM1 = (N + 31) / 32;  // 512 threads, 32 nodes, 8 waves
    const int gFG  = (N + 15) / 16;   // 256 threads, 16 nodes
    const int gFG4 = (N + 31) / 32;

    hipMemsetAsync(bcnt, 0, 512 * sizeof(int), stream);
    hipMemsetAsync(psum, 0, 512 * sizeof(float), stream);

    // ---- CSR build (by dst, col = src) + dinv
    bhist_kernel<<<gBH, 256, 0, stream>>>(dstp, bcnt, E, NB);
    bscan_kernel<<<1, 512, 0, stream>>>(bcnt, base, bfill, NB, E);
    bin_kernel<<<nbin, 256, 0, stream>>>(srcp, dstp, bfill, binned, E, NB);
    group_kernel<<<NB, 256, 0, stream>>>(binned, base, rowptr, col, dinv, N, E);

    // ---- weight prepack (after group: overwrites binned) + input scale (fp8)
    wprep12_kernel<<<64, 256, 0, stream>>>(W1, W2, Wth);
    scale_kernel<<<gN16, 256, 0, stream>>>(x, dinv, T1f8, N);

    // ---- layers 1+2: fp8 gather -> MFMA GEMM1(+b1,relu) -> GEMM2(*dinv) -> T2f8
    fgmm1_kernel<<<gFGM1, 512, 0, stream>>>(T1f8, rowptr, col, dinv, Wt1, Wt2, b1, T2f8, N);

    // ---- layer 3: fp8 gather(+b2,relu) + GEMM3(64->64, *dinv) -> T1f8
    fg_kernel<64, 16, true, 1><<<gFG, 256, 0, stream>>>(T2f8, rowptr, col, dinv, b2, W3, nullptr, T1f8, N);

    // ---- layer 4: fp8 gather(+b3,relu) + GEMM4(64->32, *dinv) -> T2f8 (32B rows)
    fg_kernel<32, 16, true, 1><<<gFG, 256, 0, stream>>>(T1f8, rowptr, col, dinv, b3, W4, nullptr, T2f8, N);

    // ---- fused gather4(+b4,relu) + fc-dot + pooled segment sums
    fg4_kernel<<<gFG4, 256, 0, stream>>>(T2f8, rowptr, col, dinv, b4, Wfc, batch, psum, pcnt, N);

    // ---- final mean + bias
    final_kernel<<<1, 256, 0, stream>>>(psum, pcnt, bfc, out, G);
}